// Round 13
// baseline (151.967 us; speedup 1.0000x reference)
//
#include <hip/hip_runtime.h>
#include <hip/hip_bf16.h>
#include <stdint.h>

using int32x4 = __attribute__((ext_vector_type(4))) int;

#define DIN 2048
#define DOUT 2048
#define NTOK 16384
#define KDIM 2048
#define NDIM 2048

#define BM 256
#define BN 128
#define BKB 64            // K-bytes per tile
#define NKT (KDIM / BKB)  // 32
#define ATILEB (BM * BKB) // 16 KB
#define BTILEB (BN * BKB) // 8 KB

typedef const __attribute__((address_space(1))) void* gp_t;
typedef __attribute__((address_space(3))) void* lp_t;

__device__ __forceinline__ void gload16(const void* g, void* l) {
    __builtin_amdgcn_global_load_lds((gp_t)g, (lp_t)l, 16, 0, 0);
}

// ---------------- Kernel 0: ternary int32 -> int8 ----------------
__global__ __launch_bounds__(256) void k_wconv(const int* __restrict__ wt,
                                               signed char* __restrict__ w8) {
    int i = blockIdx.x * 256 + threadIdx.x;
    int4 v = ((const int4*)wt)[i];
    char4 c;
    c.x = (signed char)v.x; c.y = (signed char)v.y;
    c.z = (signed char)v.z; c.w = (signed char)v.w;
    ((char4*)w8)[i] = c;
}

// ---------------- Kernel 1: LayerNorm + int8 absmax quant ----------------
__global__ __launch_bounds__(256) void k_lnq(const float* __restrict__ x,
                                             signed char* __restrict__ xq,
                                             float* __restrict__ xscale) {
    __shared__ float sm[12];
    const int row = blockIdx.x;
    const int tid = threadIdx.x;
    const float* p = x + (size_t)row * DIN;
    const float4 v0 = ((const float4*)p)[tid * 2];
    const float4 v1 = ((const float4*)p)[tid * 2 + 1];
    float vv[8] = {v0.x, v0.y, v0.z, v0.w, v1.x, v1.y, v1.z, v1.w};
    float s = 0.f, ss = 0.f;
#pragma unroll
    for (int i = 0; i < 8; i++) { s += vv[i]; ss += vv[i] * vv[i]; }
#pragma unroll
    for (int o = 32; o; o >>= 1) { s += __shfl_down(s, o); ss += __shfl_down(ss, o); }
    const int wv = tid >> 6;
    if ((tid & 63) == 0) { sm[wv] = s; sm[4 + wv] = ss; }
    __syncthreads();
    s = sm[0] + sm[1] + sm[2] + sm[3];
    ss = sm[4] + sm[5] + sm[6] + sm[7];
    const float mu = s * (1.f / DIN);
    const float var = ss * (1.f / DIN) - mu * mu;
    const float rstd = 1.f / sqrtf(var + 1e-5f);
    float am = 0.f;
#pragma unroll
    for (int i = 0; i < 8; i++) am = fmaxf(am, fabsf(vv[i] - mu));
#pragma unroll
    for (int o = 32; o; o >>= 1) am = fmaxf(am, __shfl_down(am, o));
    __syncthreads();
    if ((tid & 63) == 0) sm[8 + wv] = am;
    __syncthreads();
    am = fmaxf(fmaxf(sm[8], sm[9]), fmaxf(sm[10], sm[11]));
    const float scale = fmaxf(am * rstd, 1e-5f) * (1.f / 127.f);
    union { signed char c[8]; int2 v; } u;
#pragma unroll
    for (int i = 0; i < 8; i++) {
        float xn = (vv[i] - mu) * rstd;
        float t = rintf(xn / scale);
        t = fminf(127.f, fmaxf(-127.f, t));
        u.c[i] = (signed char)t;
    }
    ((int2*)(xq + (size_t)row * DIN))[tid] = u.v;
    if (tid == 0) xscale[row] = scale;
}

// ------- Kernel 2: 256x128 4-wave, 3-buffer, counted vmcnt(6), UNPINNED schedule -------
#define MFMA4(I, AF) \
    acc[I][0] = __builtin_amdgcn_mfma_i32_16x16x64_i8(AF, b0, acc[I][0], 0, 0, 0); \
    acc[I][1] = __builtin_amdgcn_mfma_i32_16x16x64_i8(AF, b1, acc[I][1], 0, 0, 0); \
    acc[I][2] = __builtin_amdgcn_mfma_i32_16x16x64_i8(AF, b2, acc[I][2], 0, 0, 0); \
    acc[I][3] = __builtin_amdgcn_mfma_i32_16x16x64_i8(AF, b3, acc[I][3], 0, 0, 0);

#define SCHED __builtin_amdgcn_sched_barrier(0);
#define BAR   __builtin_amdgcn_s_barrier();

template <bool B16OUT>
__global__ __launch_bounds__(256, 2) void k_gemm(const signed char* __restrict__ A,
                                                 const signed char* __restrict__ B,
                                                 const float* __restrict__ xs,
                                                 const float* __restrict__ wsc,
                                                 void* __restrict__ Cout) {
    __shared__ __align__(16) signed char lA[3][ATILEB];  // 48 KB
    __shared__ __align__(16) signed char lB[3][BTILEB];  // 24 KB
    __shared__ float s_xs[BM];
    __shared__ float s_ws[BN];

    const int tid = threadIdx.x;
    const int orig = blockIdx.x;
    const int bid = (orig & 7) * 128 + (orig >> 3);  // 1024 % 8 == 0 -> bijective
    const int bm = bid >> 4;   // 0..63
    const int bn = bid & 15;   // 0..15

    const int lane = tid & 63;
    const int wave = tid >> 6;  // 0..3
    const int wm = wave >> 1;   // 0..1 -> rows wm*128
    const int wn = wave & 1;    // 0..1 -> cols wn*64
    const int lo = lane & 15;
    const int q  = lane >> 4;

    // staging: LDS slot (row r, slot s) holds global chunk s ^ ((r>>1)&3); dst linear
    const int srow = tid >> 2;                       // 0..63
    const int gch  = (tid & 3) ^ ((srow >> 1) & 3);
    const signed char* gA = A + (size_t)(bm * BM + srow) * KDIM + gch * 16;
    const signed char* gB = B + (size_t)(bn * BN + srow) * KDIM + gch * 16;
    const int dst = tid * 16;

    // fragment read bases (slot constant per thread; row-block offsets compile-time)
    const int slot = (q ^ ((lo >> 1) & 3)) * 16;
    const int abase = (wm * 128 + lo) * BKB + slot;
    const int bbase = (wn * 64 + lo) * BKB + slot;

    s_xs[tid] = xs[bm * BM + tid];
    if (tid < BN) s_ws[tid] = wsc[bn * BN + tid];

// STAGE_A = 4 VMEM ops (rows srow,+64,+128,+192); STAGE_B = 2 ops; full stage = 6.
#define STAGE_A(T, BUF) \
    gload16(gA + (T) * BKB,                      &lA[BUF][0] + dst); \
    gload16(gA + (T) * BKB + (size_t)64  * KDIM, &lA[BUF][0] + dst + 4096); \
    gload16(gA + (T) * BKB + (size_t)128 * KDIM, &lA[BUF][0] + dst + 8192); \
    gload16(gA + (T) * BKB + (size_t)192 * KDIM, &lA[BUF][0] + dst + 12288);
#define STAGE_B(T, BUF) \
    gload16(gB + (T) * BKB,                      &lB[BUF][0] + dst); \
    gload16(gB + (T) * BKB + (size_t)64  * KDIM, &lB[BUF][0] + dst + 4096);

    // ---- prologue: stage tiles 0,1 (12 VMEM ops) ----
    STAGE_A(0, 0) STAGE_B(0, 0)
    STAGE_A(1, 1) STAGE_B(1, 1)
    asm volatile("s_waitcnt vmcnt(6)" ::: "memory");  // tile 0 landed; tile 1 in flight
    BAR

    int32x4 acc[8][4];
#pragma unroll
    for (int i = 0; i < 8; i++)
#pragma unroll
        for (int j = 0; j < 4; j++) {
            int32x4 z = {0, 0, 0, 0};
            acc[i][j] = z;
        }

    // Invariant at ITER(T) entry: outstanding VMEM ⊆ {stage(T) tail?, stage(T+1)}.
    //   vmcnt(6) forces stage(T) complete, keeps stage(T+1) (6 ops) IN FLIGHT across BAR.
    //   Then stage(T+2) into buf (T+2)%3 (readers of its old tile synced at this BAR).
    // Schedule deliberately UNPINNED (m141): only rule-#18 fences after lgkm waits.
    int cur = 0, nx = 2;
    for (int t = 0; t < NKT; ++t) {
        const signed char* lAc = &lA[cur][0];
        const signed char* lBc = &lB[cur][0];
        int32x4 a0, a1, a2, a3, a4, a5, a6, a7, b0, b1, b2, b3;

        a0 = *(const int32x4*)(lAc + abase + 0 * 1024);
        a1 = *(const int32x4*)(lAc + abase + 1 * 1024);
        a2 = *(const int32x4*)(lAc + abase + 2 * 1024);
        a3 = *(const int32x4*)(lAc + abase + 3 * 1024);
        b0 = *(const int32x4*)(lBc + bbase + 0 * 1024);
        b1 = *(const int32x4*)(lBc + bbase + 1 * 1024);
        b2 = *(const int32x4*)(lBc + bbase + 2 * 1024);
        b3 = *(const int32x4*)(lBc + bbase + 3 * 1024);
        a4 = *(const int32x4*)(lAc + abase + 4 * 1024);
        a5 = *(const int32x4*)(lAc + abase + 5 * 1024);
        a6 = *(const int32x4*)(lAc + abase + 6 * 1024);
        a7 = *(const int32x4*)(lAc + abase + 7 * 1024);
        if (t + 1 < NKT) { asm volatile("s_waitcnt vmcnt(6)" ::: "memory"); }
        else             { asm volatile("s_waitcnt vmcnt(0)" ::: "memory"); }
        BAR
        if (t + 2 < NKT) { STAGE_A(t + 2, nx) STAGE_B(t + 2, nx) }
        asm volatile("s_waitcnt lgkmcnt(4)" ::: "memory");  // a0-3,b0-3 ready
        SCHED  // rule #18: keep MFMAs below the wait
        MFMA4(0, a0) MFMA4(1, a1) MFMA4(2, a2) MFMA4(3, a3)
        asm volatile("s_waitcnt lgkmcnt(0)" ::: "memory");  // a4-7 ready
        SCHED  // rule #18
        MFMA4(4, a4) MFMA4(5, a5) MFMA4(6, a6) MFMA4(7, a7)

        cur = (cur == 2) ? 0 : cur + 1;
        nx  = (nx == 2) ? 0 : nx + 1;
    }

    // ---- epilogue: scale + store (bf16 to ws, or fp32 to d_out) ----
#pragma unroll
    for (int i = 0; i < 8; ++i) {
#pragma unroll
        for (int j = 0; j < 4; ++j) {
            const int ln = wn * 64 + j * 16 + lo;
            const float wsv = s_ws[ln];
            const size_t base = (size_t)(bm * BM + wm * 128 + i * 16 + q * 4) * NDIM + bn * BN + ln;
#pragma unroll
            for (int r = 0; r < 4; ++r) {
                const int lm = wm * 128 + i * 16 + q * 4 + r;
                const float v = (float)acc[i][j][r] * s_xs[lm] * wsv;
                if constexpr (B16OUT) {
                    ((__hip_bfloat16*)Cout)[base + (size_t)r * NDIM] = __float2bfloat16(v);
                } else {
                    ((float*)Cout)[base + (size_t)r * NDIM] = v;
                }
            }
        }
    }
}

// ---------------- Kernel 3a: output LayerNorm, bf16 in (ws) -> fp32 out ----------------
__global__ __launch_bounds__(256) void k_lnout_b(const __hip_bfloat16* __restrict__ cb,
                                                 float* __restrict__ y) {
    __shared__ float sm[8];
    const int row = blockIdx.x;
    const int tid = threadIdx.x;
    int4 raw = ((const int4*)(cb + (size_t)row * DOUT))[tid];  // 8 bf16
    union { int4 v; unsigned u[4]; } U; U.v = raw;
    float vv[8];
#pragma unroll
    for (int k = 0; k < 4; k++) {
        vv[2 * k]     = __uint_as_float(U.u[k] << 16);
        vv[2 * k + 1] = __uint_as_float(U.u[k] & 0xffff0000u);
    }
    float s = 0.f, ss = 0.f;
#pragma unroll
    for (int i = 0; i < 8; i++) { s += vv[i]; ss += vv[i] * vv[i]; }
#pragma unroll
    for (int o = 32; o; o >>= 1) { s += __shfl_down(s, o); ss += __shfl_down(ss, o); }
    const int wv = tid >> 6;
    if ((tid & 63) == 0) { sm[wv] = s; sm[4 + wv] = ss; }
    __syncthreads();
    s = sm[0] + sm[1] + sm[2] + sm[3];
    ss = sm[4] + sm[5] + sm[6] + sm[7];
    const float mu = s * (1.f / DOUT);
    const float var = ss * (1.f / DOUT) - mu * mu;
    const float rstd = 1.f / sqrtf(var + 1e-5f);
    float* p = y + (size_t)row * DOUT;
    float4 o0, o1;
    o0.x = (vv[0] - mu) * rstd; o0.y = (vv[1] - mu) * rstd;
    o0.z = (vv[2] - mu) * rstd; o0.w = (vv[3] - mu) * rstd;
    o1.x = (vv[4] - mu) * rstd; o1.y = (vv[5] - mu) * rstd;
    o1.z = (vv[6] - mu) * rstd; o1.w = (vv[7] - mu) * rstd;
    ((float4*)p)[tid * 2] = o0;
    ((float4*)p)[tid * 2 + 1] = o1;
}

// ---------------- Kernel 3b: output LayerNorm, fp32 in-place (fallback) ----------------
__global__ __launch_bounds__(256) void k_lnout(float* __restrict__ y) {
    __shared__ float sm[8];
    const int row = blockIdx.x;
    const int tid = threadIdx.x;
    float* p = y + (size_t)row * DOUT;
    float4 v0 = ((float4*)p)[tid * 2];
    float4 v1 = ((float4*)p)[tid * 2 + 1];
    float vv[8] = {v0.x, v0.y, v0.z, v0.w, v1.x, v1.y, v1.z, v1.w};
    float s = 0.f, ss = 0.f;
#pragma unroll
    for (int i = 0; i < 8; i++) { s += vv[i]; ss += vv[i] * vv[i]; }
#pragma unroll
    for (int o = 32; o; o >>= 1) { s += __shfl_down(s, o); ss += __shfl_down(ss, o); }
    const int wv = tid >> 6;
    if ((tid & 63) == 0) { sm[wv] = s; sm[4 + wv] = ss; }
    __syncthreads();
    s = sm[0] + sm[1] + sm[2] + sm[3];
    ss = sm[4] + sm[5] + sm[6] + sm[7];
    const float mu = s * (1.f / DOUT);
    const float var = ss * (1.f / DOUT) - mu * mu;
    const float rstd = 1.f / sqrtf(var + 1e-5f);
#pragma unroll
    for (int i = 0; i < 8; i++) vv[i] = (vv[i] - mu) * rstd;
    float4 o0, o1;
    o0.x = vv[0]; o0.y = vv[1]; o0.z = vv[2]; o0.w = vv[3];
    o1.x = vv[4]; o1.y = vv[5]; o1.z = vv[6]; o1.w = vv[7];
    ((float4*)p)[tid * 2] = o0;
    ((float4*)p)[tid * 2 + 1] = o1;
}

extern "C" void kernel_launch(void* const* d_in, const int* in_sizes, int n_in,
                              void* d_out, int out_size, void* d_ws, size_t ws_size,
                              hipStream_t stream) {
    const float* x = (const float*)d_in[0];
    const int* wt = (const int*)d_in[1];
    const float* wscale = (const float*)d_in[2];
    float* out = (float*)d_out;

    // ws layout: w8 @0 (4MB) | xq @4MB (32MB) | xs @36MB (64KB) | c16 @40MB (64MB)
    signed char* w8 = (signed char*)d_ws;
    signed char* xq = (signed char*)d_ws + (size_t)4 * 1024 * 1024;
    float* xs = (float*)((char*)d_ws + (size_t)36 * 1024 * 1024);
    __hip_bfloat16* c16 = (__hip_bfloat16*)((char*)d_ws + (size_t)40 * 1024 * 1024);
    const bool use16 = ws_size >= (size_t)104 * 1024 * 1024;

    k_wconv<<<(DOUT * DIN / 4) / 256, 256, 0, stream>>>(wt, w8);
    k_lnq<<<NTOK, 256, 0, stream>>>(x, xq, xs);
    if (use16) {
        k_gemm<true><<<(NTOK / BM) * (NDIM / BN), 256, 0, stream>>>(xq, w8, xs, wscale, (void*)c16);
        k_lnout_b<<<NTOK, 256, 0, stream>>>(c16, out);
    } else {
        k_gemm<false><<<(NTOK / BM) * (NDIM / BN), 256, 0, stream>>>(xq, w8, xs, wscale, (void*)out);
        k_lnout<<<NTOK, 256, 0, stream>>>(out);
    }
}

// Round 14
// 149.524 us; speedup vs baseline: 1.0163x; 1.0163x over previous
//
#include <hip/hip_runtime.h>
#include <hip/hip_bf16.h>
#include <stdint.h>

using int32x4 = __attribute__((ext_vector_type(4))) int;

#define DIN 2048
#define DOUT 2048
#define NTOK 16384
#define KDIM 2048
#define NDIM 2048

#define BM 256
#define BN 128
#define BKB 64            // K-bytes per tile
#define NKT (KDIM / BKB)  // 32
#define ATILEB (BM * BKB) // 16 KB
#define BTILEB (BN * BKB) // 8 KB

typedef const __attribute__((address_space(1))) void* gp_t;
typedef __attribute__((address_space(3))) void* lp_t;

__device__ __forceinline__ void gload16(const void* g, void* l) {
    __builtin_amdgcn_global_load_lds((gp_t)g, (lp_t)l, 16, 0, 0);
}

// ---- Kernel 1: LayerNorm + int8 absmax quant (+ fused ternary->int8 weight conv) ----
__global__ __launch_bounds__(256) void k_lnq(const float* __restrict__ x,
                                             signed char* __restrict__ xq,
                                             float* __restrict__ xscale,
                                             const int* __restrict__ wt,
                                             signed char* __restrict__ w8) {
    __shared__ float sm[12];
    const int row = blockIdx.x;
    const int tid = threadIdx.x;

    // fused weight conversion: blocks 0..2047 each convert 1024 int32 -> 1024 int8
    if (row < (DOUT * DIN / 4) / 256) {
        const int i = row * 256 + tid;
        int4 v = ((const int4*)wt)[i];
        char4 c;
        c.x = (signed char)v.x; c.y = (signed char)v.y;
        c.z = (signed char)v.z; c.w = (signed char)v.w;
        ((char4*)w8)[i] = c;
    }

    const float* p = x + (size_t)row * DIN;
    const float4 v0 = ((const float4*)p)[tid * 2];
    const float4 v1 = ((const float4*)p)[tid * 2 + 1];
    float vv[8] = {v0.x, v0.y, v0.z, v0.w, v1.x, v1.y, v1.z, v1.w};
    float s = 0.f, ss = 0.f;
#pragma unroll
    for (int i = 0; i < 8; i++) { s += vv[i]; ss += vv[i] * vv[i]; }
#pragma unroll
    for (int o = 32; o; o >>= 1) { s += __shfl_down(s, o); ss += __shfl_down(ss, o); }
    const int wv = tid >> 6;
    if ((tid & 63) == 0) { sm[wv] = s; sm[4 + wv] = ss; }
    __syncthreads();
    s = sm[0] + sm[1] + sm[2] + sm[3];
    ss = sm[4] + sm[5] + sm[6] + sm[7];
    const float mu = s * (1.f / DIN);
    const float var = ss * (1.f / DIN) - mu * mu;
    const float rstd = 1.f / sqrtf(var + 1e-5f);
    float am = 0.f;
#pragma unroll
    for (int i = 0; i < 8; i++) am = fmaxf(am, fabsf(vv[i] - mu));
#pragma unroll
    for (int o = 32; o; o >>= 1) am = fmaxf(am, __shfl_down(am, o));
    __syncthreads();
    if ((tid & 63) == 0) sm[8 + wv] = am;
    __syncthreads();
    am = fmaxf(fmaxf(sm[8], sm[9]), fmaxf(sm[10], sm[11]));
    const float scale = fmaxf(am * rstd, 1e-5f) * (1.f / 127.f);
    union { signed char c[8]; int2 v; } u;
#pragma unroll
    for (int i = 0; i < 8; i++) {
        float xn = (vv[i] - mu) * rstd;
        float t = rintf(xn / scale);
        t = fminf(127.f, fmaxf(-127.f, t));
        u.c[i] = (signed char)t;
    }
    ((int2*)(xq + (size_t)row * DIN))[tid] = u.v;
    if (tid == 0) xscale[row] = scale;
}

// ------- Kernel 2: 256x128 4-wave, 3-buffer, counted vmcnt(6), race-fixed -------
#define MFMA4(I, AF) \
    acc[I][0] = __builtin_amdgcn_mfma_i32_16x16x64_i8(AF, b0, acc[I][0], 0, 0, 0); \
    acc[I][1] = __builtin_amdgcn_mfma_i32_16x16x64_i8(AF, b1, acc[I][1], 0, 0, 0); \
    acc[I][2] = __builtin_amdgcn_mfma_i32_16x16x64_i8(AF, b2, acc[I][2], 0, 0, 0); \
    acc[I][3] = __builtin_amdgcn_mfma_i32_16x16x64_i8(AF, b3, acc[I][3], 0, 0, 0);

#define SCHED __builtin_amdgcn_sched_barrier(0);
#define BAR   __builtin_amdgcn_s_barrier();

template <bool B16OUT>
__global__ __launch_bounds__(256, 2) void k_gemm(const signed char* __restrict__ A,
                                                 const signed char* __restrict__ B,
                                                 const float* __restrict__ xs,
                                                 const float* __restrict__ wsc,
                                                 void* __restrict__ Cout) {
    __shared__ __align__(16) signed char lA[3][ATILEB];  // 48 KB
    __shared__ __align__(16) signed char lB[3][BTILEB];  // 24 KB
    __shared__ float s_xs[BM];
    __shared__ float s_ws[BN];

    const int tid = threadIdx.x;
    const int orig = blockIdx.x;
    const int bid = (orig & 7) * 128 + (orig >> 3);  // 1024 % 8 == 0 -> bijective
    const int bm = bid >> 4;   // 0..63
    const int bn = bid & 15;   // 0..15

    const int lane = tid & 63;
    const int wave = tid >> 6;  // 0..3
    const int wm = wave >> 1;   // 0..1 -> rows wm*128
    const int wn = wave & 1;    // 0..1 -> cols wn*64
    const int lo = lane & 15;
    const int q  = lane >> 4;

    // staging: LDS slot (row r, slot s) holds global chunk s ^ ((r>>1)&3); dst linear
    const int srow = tid >> 2;                       // 0..63
    const int gch  = (tid & 3) ^ ((srow >> 1) & 3);
    const signed char* gA = A + (size_t)(bm * BM + srow) * KDIM + gch * 16;
    const signed char* gB = B + (size_t)(bn * BN + srow) * KDIM + gch * 16;
    const int dst = tid * 16;

    // fragment read bases (slot constant per thread; row-block offsets compile-time)
    const int slot = (q ^ ((lo >> 1) & 3)) * 16;
    const int abase = (wm * 128 + lo) * BKB + slot;
    const int bbase = (wn * 64 + lo) * BKB + slot;

    s_xs[tid] = xs[bm * BM + tid];
    if (tid < BN) s_ws[tid] = wsc[bn * BN + tid];

// STAGE_A = 4 VMEM ops (rows srow,+64,+128,+192); STAGE_B = 2 ops; full stage = 6.
#define STAGE_A(T, BUF) \
    gload16(gA + (T) * BKB,                      &lA[BUF][0] + dst); \
    gload16(gA + (T) * BKB + (size_t)64  * KDIM, &lA[BUF][0] + dst + 4096); \
    gload16(gA + (T) * BKB + (size_t)128 * KDIM, &lA[BUF][0] + dst + 8192); \
    gload16(gA + (T) * BKB + (size_t)192 * KDIM, &lA[BUF][0] + dst + 12288);
#define STAGE_B(T, BUF) \
    gload16(gB + (T) * BKB,                      &lB[BUF][0] + dst); \
    gload16(gB + (T) * BKB + (size_t)64  * KDIM, &lB[BUF][0] + dst + 4096);

    // ---- prologue: stage tiles 0,1 (12 VMEM ops) ----
    STAGE_A(0, 0) STAGE_B(0, 0)
    STAGE_A(1, 1) STAGE_B(1, 1)
    asm volatile("s_waitcnt vmcnt(6)" ::: "memory");  // tile 0 landed; tile 1 in flight
    BAR

    int32x4 acc[8][4];
#pragma unroll
    for (int i = 0; i < 8; i++)
#pragma unroll
        for (int j = 0; j < 4; j++) {
            int32x4 z = {0, 0, 0, 0};
            acc[i][j] = z;
        }

    // Invariant at ITER(T) entry: outstanding VMEM = {stage(T), stage(T+1)} (<=12 ops).
    //   vmcnt FIRST (race fix): drain to 6 -> stage(T) complete BEFORE tile-T ds_reads;
    //   stage(T+1) (6 ops) stays IN FLIGHT across the barrier (counted wait, T4).
    //   stage(T+2) after BAR into buf (T+2)%3: its previous readers (ITER(T-1)) were
    //   drained by that iter's lgkmcnt(0) before this BAR -> WAR safe.
    int cur = 0, nx = 2;
    for (int t = 0; t < NKT; ++t) {
        const signed char* lAc = &lA[cur][0];
        const signed char* lBc = &lB[cur][0];
        int32x4 a0, a1, a2, a3, a4, a5, a6, a7, b0, b1, b2, b3;

        if (t < NKT - 1) { asm volatile("s_waitcnt vmcnt(6)" ::: "memory"); }
        else             { asm volatile("s_waitcnt vmcnt(0)" ::: "memory"); }
        a0 = *(const int32x4*)(lAc + abase + 0 * 1024);
        a1 = *(const int32x4*)(lAc + abase + 1 * 1024);
        a2 = *(const int32x4*)(lAc + abase + 2 * 1024);
        a3 = *(const int32x4*)(lAc + abase + 3 * 1024);
        b0 = *(const int32x4*)(lBc + bbase + 0 * 1024);
        b1 = *(const int32x4*)(lBc + bbase + 1 * 1024);
        b2 = *(const int32x4*)(lBc + bbase + 2 * 1024);
        b3 = *(const int32x4*)(lBc + bbase + 3 * 1024);
        a4 = *(const int32x4*)(lAc + abase + 4 * 1024);
        a5 = *(const int32x4*)(lAc + abase + 5 * 1024);
        a6 = *(const int32x4*)(lAc + abase + 6 * 1024);
        a7 = *(const int32x4*)(lAc + abase + 7 * 1024);
        BAR
        if (t + 2 < NKT) { STAGE_A(t + 2, nx) STAGE_B(t + 2, nx) }
        asm volatile("s_waitcnt lgkmcnt(4)" ::: "memory");  // a0-3,b0-3 ready
        SCHED  // rule #18: keep MFMAs below the wait
        MFMA4(0, a0) MFMA4(1, a1) MFMA4(2, a2) MFMA4(3, a3)
        asm volatile("s_waitcnt lgkmcnt(0)" ::: "memory");  // a4-7 ready
        SCHED  // rule #18
        MFMA4(4, a4) MFMA4(5, a5) MFMA4(6, a6) MFMA4(7, a7)

        cur = (cur == 2) ? 0 : cur + 1;
        nx  = (nx == 2) ? 0 : nx + 1;
    }

    // ---- epilogue: scale + store (bf16 to ws, or fp32 to d_out) ----
#pragma unroll
    for (int i = 0; i < 8; ++i) {
#pragma unroll
        for (int j = 0; j < 4; ++j) {
            const int ln = wn * 64 + j * 16 + lo;
            const float wsv = s_ws[ln];
            const size_t base = (size_t)(bm * BM + wm * 128 + i * 16 + q * 4) * NDIM + bn * BN + ln;
#pragma unroll
            for (int r = 0; r < 4; ++r) {
                const int lm = wm * 128 + i * 16 + q * 4 + r;
                const float v = (float)acc[i][j][r] * s_xs[lm] * wsv;
                if constexpr (B16OUT) {
                    ((__hip_bfloat16*)Cout)[base + (size_t)r * NDIM] = __float2bfloat16(v);
                } else {
                    ((float*)Cout)[base + (size_t)r * NDIM] = v;
                }
            }
        }
    }
}

// ---------------- Kernel 3a: output LayerNorm, bf16 in (ws) -> fp32 out ----------------
__global__ __launch_bounds__(256) void k_lnout_b(const __hip_bfloat16* __restrict__ cb,
                                                 float* __restrict__ y) {
    __shared__ float sm[8];
    const int row = blockIdx.x;
    const int tid = threadIdx.x;
    int4 raw = ((const int4*)(cb + (size_t)row * DOUT))[tid];  // 8 bf16
    union { int4 v; unsigned u[4]; } U; U.v = raw;
    float vv[8];
#pragma unroll
    for (int k = 0; k < 4; k++) {
        vv[2 * k]     = __uint_as_float(U.u[k] << 16);
        vv[2 * k + 1] = __uint_as_float(U.u[k] & 0xffff0000u);
    }
    float s = 0.f, ss = 0.f;
#pragma unroll
    for (int i = 0; i < 8; i++) { s += vv[i]; ss += vv[i] * vv[i]; }
#pragma unroll
    for (int o = 32; o; o >>= 1) { s += __shfl_down(s, o); ss += __shfl_down(ss, o); }
    const int wv = tid >> 6;
    if ((tid & 63) == 0) { sm[wv] = s; sm[4 + wv] = ss; }
    __syncthreads();
    s = sm[0] + sm[1] + sm[2] + sm[3];
    ss = sm[4] + sm[5] + sm[6] + sm[7];
    const float mu = s * (1.f / DOUT);
    const float var = ss * (1.f / DOUT) - mu * mu;
    const float rstd = 1.f / sqrtf(var + 1e-5f);
    float* p = y + (size_t)row * DOUT;
    float4 o0, o1;
    o0.x = (vv[0] - mu) * rstd; o0.y = (vv[1] - mu) * rstd;
    o0.z = (vv[2] - mu) * rstd; o0.w = (vv[3] - mu) * rstd;
    o1.x = (vv[4] - mu) * rstd; o1.y = (vv[5] - mu) * rstd;
    o1.z = (vv[6] - mu) * rstd; o1.w = (vv[7] - mu) * rstd;
    ((float4*)p)[tid * 2] = o0;
    ((float4*)p)[tid * 2 + 1] = o1;
}

// ---------------- Kernel 3b: output LayerNorm, fp32 in-place (fallback) ----------------
__global__ __launch_bounds__(256) void k_lnout(float* __restrict__ y) {
    __shared__ float sm[8];
    const int row = blockIdx.x;
    const int tid = threadIdx.x;
    float* p = y + (size_t)row * DOUT;
    float4 v0 = ((float4*)p)[tid * 2];
    float4 v1 = ((float4*)p)[tid * 2 + 1];
    float vv[8] = {v0.x, v0.y, v0.z, v0.w, v1.x, v1.y, v1.z, v1.w};
    float s = 0.f, ss = 0.f;
#pragma unroll
    for (int i = 0; i < 8; i++) { s += vv[i]; ss += vv[i] * vv[i]; }
#pragma unroll
    for (int o = 32; o; o >>= 1) { s += __shfl_down(s, o); ss += __shfl_down(ss, o); }
    const int wv = tid >> 6;
    if ((tid & 63) == 0) { sm[wv] = s; sm[4 + wv] = ss; }
    __syncthreads();
    s = sm[0] + sm[1] + sm[2] + sm[3];
    ss = sm[4] + sm[5] + sm[6] + sm[7];
    const float mu = s * (1.f / DOUT);
    const float var = ss * (1.f / DOUT) - mu * mu;
    const float rstd = 1.f / sqrtf(var + 1e-5f);
#pragma unroll
    for (int i = 0; i < 8; i++) vv[i] = (vv[i] - mu) * rstd;
    float4 o0, o1;
    o0.x = vv[0]; o0.y = vv[1]; o0.z = vv[2]; o0.w = vv[3];
    o1.x = vv[4]; o1.y = vv[5]; o1.z = vv[6]; o1.w = vv[7];
    ((float4*)p)[tid * 2] = o0;
    ((float4*)p)[tid * 2 + 1] = o1;
}

extern "C" void kernel_launch(void* const* d_in, const int* in_sizes, int n_in,
                              void* d_out, int out_size, void* d_ws, size_t ws_size,
                              hipStream_t stream) {
    const float* x = (const float*)d_in[0];
    const int* wt = (const int*)d_in[1];
    const float* wscale = (const float*)d_in[2];
    float* out = (float*)d_out;

    // ws layout: w8 @0 (4MB) | xq @4MB (32MB) | xs @36MB (64KB) | c16 @40MB (64MB)
    signed char* w8 = (signed char*)d_ws;
    signed char* xq = (signed char*)d_ws + (size_t)4 * 1024 * 1024;
    float* xs = (float*)((char*)d_ws + (size_t)36 * 1024 * 1024);
    __hip_bfloat16* c16 = (__hip_bfloat16*)((char*)d_ws + (size_t)40 * 1024 * 1024);
    const bool use16 = ws_size >= (size_t)104 * 1024 * 1024;

    k_lnq<<<NTOK, 256, 0, stream>>>(x, xq, xs, wt, w8);
    if (use16) {
        k_gemm<true><<<(NTOK / BM) * (NDIM / BN), 256, 0, stream>>>(xq, w8, xs, wscale, (void*)c16);
        k_lnout_b<<<NTOK, 256, 0, stream>>>(c16, out);
    } else {
        k_gemm<false><<<(NTOK / BM) * (NDIM / BN), 256, 0, stream>>>(xq, w8, xs, wscale, (void*)out);
        k_lnout<<<NTOK, 256, 0, stream>>>(out);
    }
}